// Round 13
// baseline (80.805 us; speedup 1.0000x reference)
//
#include <hip/hip_runtime.h>
#include <math.h>

// BayesPredictor: inputs [B,D] f32, alphas [B] f32, data [N,D] f32
#define BB 32
#define DD 128
#define NN 32768

#define NB 512              // k1 blocks
#define RPB 64              // data rows per block
#define NP NB               // partials per b
// ws map: x0 partials [b][bid][128] f32 contiguous; packed ms float2 [b][bid] after
#define WS_MS_OFF ((size_t)BB * NB * DD)

typedef __attribute__((ext_vector_type(8))) short bf16x8;
typedef __attribute__((ext_vector_type(4))) float f32x4;

// ---- LDS arena (bytes). Swizzle: 16B-granule XOR ((row&7)<<4) on every tile.
#define O_RH   0            // rows hi  bf16 [64][128] pitch 256
#define O_RL   16384        // rows lo  bf16 [64][128] pitch 256
#define O_INH  32768        // inputs hi bf16 [32][128] pitch 256
#define O_INL  40960        // inputs lo
#define O_RT   49152        // rows^T hi bf16 [128][64] pitch 128
#define O_D1   65536        // L f32 [64 r][33] pitch 132B (pad kills bank conflicts)
#define O_NRM  73984        // 64 row norms f32
#define O_PT   O_INH        // P^T bf16 [32 b][64 r] pitch 128 (overlays inh after GEMM1)
#define O_X0   O_RH         // x0 f32 [32 b][128 d] pitch 512 (overlays Rh after GEMM1)
#define ARENA  74240        // 2 blocks/CU

__device__ __forceinline__ unsigned bf16_rne(float x) {
    unsigned u = __builtin_bit_cast(unsigned, x);
    return (u + 0x7FFFu + ((u >> 16) & 1u)) >> 16;
}
__device__ __forceinline__ float bf16f(unsigned h) {
    return __builtin_bit_cast(float, h << 16);
}
__device__ __forceinline__ unsigned pk2(float a, float b) {
    return bf16_rne(a) | (bf16_rne(b) << 16);
}

// ---------------- kernel 1: per-block (64 rows) flash step via split-bf16 MFMA ----------------
// r11 structure, but GEMM-1 is full-K per wave (no k-split partial merge through LDS).
__global__ __launch_bounds__(256) void bayes_k1(
    const float* __restrict__ inputs, const float* __restrict__ alphas,
    const float* __restrict__ data, float* __restrict__ ws)
{
    __shared__ __align__(16) char arena[ARENA];

    const int tid  = threadIdx.x;
    const int lane = tid & 63;
    const int wv   = tid >> 6;       // 0..3
    const int ln   = lane & 15;
    const int g    = lane >> 4;      // 0..3
    const int bid  = blockIdx.x;

    // ---- stage A: rows -> Rh/Rl (hi/lo split) + f32 norms. t: r=t>>2, 32-float chunk c4.
    {
        const int r = tid >> 2, c4 = tid & 3;
        const float4* gp = (const float4*)(data + ((size_t)bid * RPB + r) * DD + c4 * 32);
        float v[32];
        #pragma unroll
        for (int i = 0; i < 8; ++i) {
            const float4 t4 = gp[i];
            v[4*i+0] = t4.x; v[4*i+1] = t4.y; v[4*i+2] = t4.z; v[4*i+3] = t4.w;
        }
        float nn = 0.0f;
        #pragma unroll
        for (int i = 0; i < 32; ++i) nn = fmaf(v[i], v[i], nn);
        nn += __shfl_xor(nn, 1);
        nn += __shfl_xor(nn, 2);
        if (c4 == 0) *(float*)(arena + O_NRM + r * 4) = nn;

        const int swz = (r & 7) << 4;
        #pragma unroll
        for (int u = 0; u < 4; ++u) {       // 4 granules of 8 bf16
            unsigned hw[4], lw[4];
            #pragma unroll
            for (int j = 0; j < 4; ++j) {
                const float a = v[u*8 + 2*j], b = v[u*8 + 2*j + 1];
                const unsigned ah = bf16_rne(a), bh = bf16_rne(b);
                hw[j] = ah | (bh << 16);
                lw[j] = pk2(a - bf16f(ah), b - bf16f(bh));
            }
            const int go = (c4 * 64 + u * 16) ^ swz;
            *(uint4*)(arena + O_RH + r * 256 + go) = make_uint4(hw[0], hw[1], hw[2], hw[3]);
            *(uint4*)(arena + O_RL + r * 256 + go) = make_uint4(lw[0], lw[1], lw[2], lw[3]);
        }
    }

    // ---- stage A2: inputs -> inh/inl. t: b=t>>3, 16-float chunk c8.
    {
        const int b = tid >> 3, c8 = tid & 7;
        const float4* gp = (const float4*)(inputs + b * DD + c8 * 16);
        float v[16];
        #pragma unroll
        for (int i = 0; i < 4; ++i) {
            const float4 t4 = gp[i];
            v[4*i+0] = t4.x; v[4*i+1] = t4.y; v[4*i+2] = t4.z; v[4*i+3] = t4.w;
        }
        const int swz = (b & 7) << 4;
        #pragma unroll
        for (int u = 0; u < 2; ++u) {
            unsigned hw[4], lw[4];
            #pragma unroll
            for (int j = 0; j < 4; ++j) {
                const float a = v[u*8 + 2*j], bb = v[u*8 + 2*j + 1];
                const unsigned ah = bf16_rne(a), bh = bf16_rne(bb);
                hw[j] = ah | (bh << 16);
                lw[j] = pk2(a - bf16f(ah), bb - bf16f(bh));
            }
            const int go = (c8 * 32 + u * 16) ^ swz;
            *(uint4*)(arena + O_INH + b * 256 + go) = make_uint4(hw[0], hw[1], hw[2], hw[3]);
            *(uint4*)(arena + O_INL + b * 256 + go) = make_uint4(lw[0], lw[1], lw[2], lw[3]);
        }
    }

    // ---- stage B: transposed re-read (L2-hot) -> RT hi. t: d=t>>1, r-half rh.
    {
        const int d = tid >> 1, rh = tid & 1;
        const float* gc = data + ((size_t)bid * RPB + rh * 32) * DD + d;
        const int swz = (d & 7) << 4;
        #pragma unroll
        for (int u = 0; u < 4; ++u) {       // granule u: local rows u*8..u*8+7
            unsigned w[4];
            #pragma unroll
            for (int j = 0; j < 4; ++j)
                w[j] = pk2(gc[(u*8 + 2*j) * DD], gc[(u*8 + 2*j + 1) * DD]);
            *(uint4*)(arena + O_RT + d * 128 + ((rh * 64 + u * 16) ^ swz)) =
                make_uint4(w[0], w[1], w[2], w[3]);
        }
    }
    __syncthreads();   // B1

    // ---- GEMM-1: L[r,b] = rows · in^T, FULL K per wave; wave owns r-tile wv x both b-tiles
    {
        const int r = wv * 16 + ln;
        f32x4 acc1[2];
        #pragma unroll
        for (int nt = 0; nt < 2; ++nt)
            #pragma unroll
            for (int i = 0; i < 4; ++i) acc1[nt][i] = 0.0f;

        #pragma unroll
        for (int ks = 0; ks < 4; ++ks) {
            const int kbyte = ks * 64 + g * 16;
            const bf16x8 Ah = *(const bf16x8*)(arena + O_RH + r * 256 + (kbyte ^ ((r & 7) << 4)));
            const bf16x8 Al = *(const bf16x8*)(arena + O_RL + r * 256 + (kbyte ^ ((r & 7) << 4)));
            #pragma unroll
            for (int nt = 0; nt < 2; ++nt) {
                const int n = nt * 16 + ln;
                const bf16x8 Bh = *(const bf16x8*)(arena + O_INH + n * 256 + (kbyte ^ ((n & 7) << 4)));
                const bf16x8 Bl = *(const bf16x8*)(arena + O_INL + n * 256 + (kbyte ^ ((n & 7) << 4)));
                acc1[nt] = __builtin_amdgcn_mfma_f32_16x16x32_bf16(Ah, Bh, acc1[nt], 0, 0, 0);
                acc1[nt] = __builtin_amdgcn_mfma_f32_16x16x32_bf16(Al, Bh, acc1[nt], 0, 0, 0);
                acc1[nt] = __builtin_amdgcn_mfma_f32_16x16x32_bf16(Ah, Bl, acc1[nt], 0, 0, 0);
            }
        }
        #pragma unroll
        for (int nt = 0; nt < 2; ++nt)
            #pragma unroll
            for (int i = 0; i < 4; ++i)
                *(float*)(arena + O_D1 + ((wv * 16 + g * 4 + i) * 33 + nt * 16 + ln) * 4) = acc1[nt][i];
    }
    __syncthreads();   // B2: full L ready

    // ---- softmax (waves 0,1): column b over all 64 rows, write P^T bf16 + packed m,s
    if (wv < 2) {
        const int b = wv * 16 + ln;
        const float alpha = alphas[b];
        const float var = 1.0f - alpha;
        const float c1 = sqrtf(alpha) / var;
        const float c2 = 0.5f * alpha / var;

        float lg[16];
        float mx = -1e30f;
        #pragma unroll
        for (int j = 0; j < 16; ++j) {
            const int r = g * 16 + j;
            const float L  = *(const float*)(arena + O_D1 + (r * 33 + b) * 4);
            const float nr = *(const float*)(arena + O_NRM + r * 4);
            lg[j] = fmaf(c1, L, -c2 * nr);
            mx = fmaxf(mx, lg[j]);
        }
        mx = fmaxf(mx, __shfl_xor(mx, 16));
        mx = fmaxf(mx, __shfl_xor(mx, 32));

        float e[16];
        float ss = 0.0f;
        #pragma unroll
        for (int j = 0; j < 16; ++j) { e[j] = __expf(lg[j] - mx); ss += e[j]; }
        ss += __shfl_xor(ss, 16);
        ss += __shfl_xor(ss, 32);

        const int swz = (b & 7) << 4;
        #pragma unroll
        for (int jj = 0; jj < 2; ++jj) {
            *(uint4*)(arena + O_PT + b * 128 + ((g * 32 + jj * 16) ^ swz)) =
                make_uint4(pk2(e[jj*8+0], e[jj*8+1]), pk2(e[jj*8+2], e[jj*8+3]),
                           pk2(e[jj*8+4], e[jj*8+5]), pk2(e[jj*8+6], e[jj*8+7]));
        }
        if (g == 0)
            *(float2*)(ws + WS_MS_OFF + ((size_t)b * NB + bid) * 2) = make_float2(mx, ss);
    }
    __syncthreads();   // B3: PT ready

    // ---- PV: x0^T[d,b] = rows^T(hi) · P  (K = 64 rows, d split across 4 waves)
    {
        f32x4 acc2[2][2];
        #pragma unroll
        for (int a = 0; a < 2; ++a)
            #pragma unroll
            for (int c = 0; c < 2; ++c)
                #pragma unroll
                for (int i = 0; i < 4; ++i) acc2[a][c][i] = 0.0f;

        #pragma unroll
        for (int ks = 0; ks < 2; ++ks) {
            bf16x8 Bp[2];
            #pragma unroll
            for (int nt = 0; nt < 2; ++nt) {
                const int b2 = nt * 16 + ln;
                Bp[nt] = *(const bf16x8*)(arena + O_PT + b2 * 128 +
                                          ((ks * 64 + g * 16) ^ ((b2 & 7) << 4)));
            }
            #pragma unroll
            for (int mt2 = 0; mt2 < 2; ++mt2) {
                const int d = wv * 32 + mt2 * 16 + ln;
                const bf16x8 Ar = *(const bf16x8*)(arena + O_RT + d * 128 +
                                                   ((ks * 64 + g * 16) ^ ((d & 7) << 4)));
                #pragma unroll
                for (int nt = 0; nt < 2; ++nt)
                    acc2[mt2][nt] = __builtin_amdgcn_mfma_f32_16x16x32_bf16(Ar, Bp[nt], acc2[mt2][nt], 0, 0, 0);
            }
        }
        // x0 bounce -> LDS [b][d] f32 (overlays Rh; Rh dead since GEMM-1)
        #pragma unroll
        for (int mt2 = 0; mt2 < 2; ++mt2)
            #pragma unroll
            for (int nt = 0; nt < 2; ++nt) {
                const int b = nt * 16 + ln;
                const int d0 = wv * 32 + mt2 * 16 + g * 4;
                *(f32x4*)(arena + O_X0 + b * 512 + ((d0 * 4) ^ ((b & 7) << 4))) = acc2[mt2][nt];
            }
    }
    __syncthreads();   // B4

    // ---- coalesced partial write: ws[b][bid][0..127] (contiguous)
    {
        const int b = tid >> 3, c8 = tid & 7;
        const int swz = (b & 7) << 4;
        float* dst = ws + ((size_t)b * NB + bid) * DD + c8 * 16;
        #pragma unroll
        for (int u = 0; u < 4; ++u) {
            const f32x4 v = *(const f32x4*)(arena + O_X0 + b * 512 + ((c8 * 64 + u * 16) ^ swz));
            *(f32x4*)(dst + u * 4) = v;
        }
    }
}

// ---------------- kernel 2: cross-block softmax combine + output (256 blocks) ----------------
__global__ __launch_bounds__(256) void bayes_k2(
    const float* __restrict__ inputs, const float* __restrict__ alphas,
    const float* __restrict__ ws, float* __restrict__ out)
{
    const int b   = blockIdx.x >> 3;   // 0..31
    const int seg = blockIdx.x & 7;    // 16-d segment
    const int tid = threadIdx.x;

    __shared__ float e_s[NP];          // 512 scale factors
    __shared__ float red_s[16];
    __shared__ float part[16][17];     // +1 pad: conflict-free column reduce

    // packed m,s: 512 float2, contiguous per b (4 KB)
    float mi[2], si[2];
    #pragma unroll
    for (int q = 0; q < 2; ++q) {
        const float2 v = *(const float2*)(ws + WS_MS_OFF + ((size_t)b * NP + tid + q * 256) * 2);
        mi[q] = v.x; si[q] = v.y;
    }

    float mm = fmaxf(mi[0], mi[1]);
    #pragma unroll
    for (int off = 1; off <= 32; off <<= 1) mm = fmaxf(mm, __shfl_xor(mm, off));
    if ((tid & 63) == 0) red_s[tid >> 6] = mm;
    __syncthreads();
    const float M = fmaxf(fmaxf(red_s[0], red_s[1]), fmaxf(red_s[2], red_s[3]));

    float ss = 0.0f;
    #pragma unroll
    for (int q = 0; q < 2; ++q) {
        const float ei = __expf(mi[q] - M);
        e_s[tid + q * 256] = ei;
        ss = fmaf(si[q], ei, ss);
    }
    #pragma unroll
    for (int off = 1; off <= 32; off <<= 1) ss += __shfl_xor(ss, off);
    if ((tid & 63) == 0) red_s[8 + (tid >> 6)] = ss;
    __syncthreads();
    const float S = (red_s[8] + red_s[9]) + (red_s[10] + red_s[11]);

    // gather: 16 d-values, 16-way split over 512 partials (32 each), coalesced,
    // 4 independent FMA chains to hide L2/L3 latency
    const int dd = tid & 15, ii = tid >> 4;
    const int d  = seg * 16 + dd;
    const float* xb = ws + (size_t)b * NP * DD + d;
    float xa = 0.0f, xbv = 0.0f, xc = 0.0f, xd = 0.0f;
    #pragma unroll 2
    for (int k = 0; k < 32; k += 4) {
        const int i0 = ii + (k + 0) * 16;
        const int i1 = ii + (k + 1) * 16;
        const int i2 = ii + (k + 2) * 16;
        const int i3 = ii + (k + 3) * 16;
        xa  = fmaf(e_s[i0], xb[(size_t)i0 * DD], xa);
        xbv = fmaf(e_s[i1], xb[(size_t)i1 * DD], xbv);
        xc  = fmaf(e_s[i2], xb[(size_t)i2 * DD], xc);
        xd  = fmaf(e_s[i3], xb[(size_t)i3 * DD], xd);
    }
    part[ii][dd] = (xa + xbv) + (xc + xd);
    __syncthreads();

    if (tid < 16) {
        float x0 = 0.0f;
        #pragma unroll
        for (int p = 0; p < 16; ++p) x0 += part[p][tid];
        x0 /= S;
        const float alpha = alphas[b];
        const float sa  = sqrtf(alpha);
        const float var = 1.0f - alpha;
        const int dout  = seg * 16 + tid;
        out[b * DD + dout] = (inputs[b * DD + dout] - sa * x0) / sqrtf(var);
    }
}

extern "C" void kernel_launch(void* const* d_in, const int* in_sizes, int n_in,
                              void* d_out, int out_size, void* d_ws, size_t ws_size,
                              hipStream_t stream)
{
    const float* inputs = (const float*)d_in[0];   // [B,D]
    const float* alphas = (const float*)d_in[1];   // [B]
    const float* data   = (const float*)d_in[2];   // [N,D]
    float* out = (float*)d_out;
    float* ws  = (float*)d_ws;                     // 8.4 MB x0 + 128 KB ms

    bayes_k1<<<NB, 256, 0, stream>>>(inputs, alphas, data, ws);
    bayes_k2<<<BB * 8, 256, 0, stream>>>(inputs, alphas, ws, out);
}